// Round 14
// baseline (505.884 us; speedup 1.0000x reference)
//
#include <hip/hip_runtime.h>

#define BATCH 256
#define SEQ 2048
#define NT 48
#define START_TAG 46
#define END_TAG 47
#define LN2f  0.6931471805599453f

// ws layout
#define TAF16 0        // K16 A-frags exp(trans) bf16: [9][64] x 8B  = 4608
#define TBF   4608     // B-frag exp(trans) f32: [9][64] x 16B       = 9216
#define TCUM  13824    // prefix sums: int cum[257] (cum[0]=0)       = 1028
#define TSC   16384    // per-chunk log2 scales: [B][NCH<=128] f32   <=128KiB
#define TW    163840   // chunk matrices M^T bf16: [B][NCH][48][48]

typedef float v2f __attribute__((ext_vector_type(2)));
typedef float v4f __attribute__((ext_vector_type(4)));
typedef short s16x4 __attribute__((ext_vector_type(4)));
typedef unsigned int u32;
typedef u32 u32x2 __attribute__((ext_vector_type(2)));
typedef u32 u32x4 __attribute__((ext_vector_type(4)));

__device__ __forceinline__ u32 pkbf(float a, float b) {
    u32 r;
    asm("v_cvt_pk_bf16_f32 %0, %1, %2" : "=v"(r) : "v"(a), "v"(b));
    return r;
}
__device__ __forceinline__ float bflo(u32 w) { return __builtin_bit_cast(float, w << 16); }
__device__ __forceinline__ float bfhi(u32 w) { return __builtin_bit_cast(float, w & 0xffff0000u); }

__device__ __forceinline__ float rfl(float x) {
    return __builtin_bit_cast(float,
        __builtin_amdgcn_readfirstlane(__builtin_bit_cast(int, x)));
}

__device__ __forceinline__ v4f mfma16_z(s16x4 a, s16x4 b, v4f z) {
    v4f d;
    asm volatile("v_mfma_f32_16x16x16_bf16 %0, %2, %3, %1"
                 : "=&v"(d) : "v"(z), "v"(a), "v"(b));
    return d;
}
__device__ __forceinline__ void mfma16_acc(v4f& acc, s16x4 a, s16x4 b) {
    asm volatile("v_mfma_f32_16x16x16_bf16 %0, %1, %2, %0"
                 : "+v"(acc) : "v"(a), "v"(b));
}

// ---------------------------------------------------------------------------
// Kernel 0: exp(trans) fragments + chunk-count prefix sums (chunk = 1<<shift
// steps).  A-frag (I,K): lane holds E[I*16+(l&15)][K*16+(l>>4)*4+i], bf16.
// B-frag (K,J): lane holds E[K*16+(l>>4)*4+i][J*16+(l&15)], f32.
// ---------------------------------------------------------------------------
__global__ void __launch_bounds__(64)
crf_setup(const float* __restrict__ trans, const int* __restrict__ seqlen,
          void* ws, int shift) {
    __shared__ float el[NT * NT];
    const int lane = threadIdx.x, ln = lane & 15, g = lane >> 4;
    #pragma unroll
    for (int m = 0; m < 36; ++m) {
        int idx = lane + 64 * m;
        el[idx] = __expf(trans[idx]);
    }
    u32x2* AF = (u32x2*)((char*)ws + TAF16);
    v4f*   BF = (v4f*)((char*)ws + TBF);
    #pragma unroll
    for (int I = 0; I < 3; ++I)
        #pragma unroll
        for (int K = 0; K < 3; ++K) {
            const v4f ev = *(const v4f*)&el[(I * 16 + ln) * NT + K * 16 + g * 4];
            AF[(I * 3 + K) * 64 + lane] = (u32x2){pkbf(ev.x, ev.y), pkbf(ev.z, ev.w)};
        }
    #pragma unroll
    for (int K = 0; K < 3; ++K)
        #pragma unroll
        for (int J = 0; J < 3; ++J) {
            v4f v;
            #pragma unroll
            for (int i = 0; i < 4; ++i)
                v[i] = el[(K * 16 + g * 4 + i) * NT + J * 16 + ln];
            BF[(K * 3 + J) * 64 + lane] = v;
        }
    if (lane == 0) {
        int* cum = (int*)((char*)ws + TCUM);
        int acc = 0, mask = (1 << shift) - 1;
        for (int b = 0; b < BATCH; ++b) {
            cum[b] = acc;
            int L = seqlen[b];
            if (L < 1) L = 1;
            if (L > SEQ) L = SEQ;
            acc += (L + mask) >> shift;
        }
        cum[BATCH] = acc;
    }
}

// ---------------------------------------------------------------------------
// Kernel 1 (compacted, templated chunk size): wave widx handles the widx-th
// ACTIVE chunk (binary search over cum[]).  Per chunk: LCH_-step K16 MFMA
// chain (r13-proven): acc = E*M (27 MFMA, 3 levels x 9, asm-pinned),
// gn = raw P00, M' = acc .* (em * 1/gn_prev), Lc += log2(gn) lagged.
// Emissions pre-exp'd into wave-private LDS.
// LCH16: 12.3KB LDS/WG -> __launch_bounds__(256,8) = 8 WG/CU (32 waves/CU);
// LCH32: 24.6KB -> (256,6) = 6 WG/CU.  r13 showed throughput ~ residency.
// ---------------------------------------------------------------------------
template<int LCH_, int NCH_>
__global__ void __launch_bounds__(256, (LCH_ == 16 ? 8 : 6))
crf_phase1c(const float* __restrict__ feat, const int* __restrict__ seqlen,
            void* __restrict__ ws) {
    const int wid = threadIdx.x >> 6;
    const int widx = blockIdx.x * 4 + wid;
    const int* cum = (const int*)((const char*)ws + TCUM);
    if (widx >= cum[BATCH]) return;

    int lo = 0, hi = BATCH;          // invariant: cum[lo] <= widx < cum[hi]
    #pragma unroll
    for (int it = 0; it < 8; ++it) {
        int mid = (lo + hi) >> 1;
        if (cum[mid] <= widx) lo = mid; else hi = mid;
    }
    const int b = lo;
    const int c = widx - cum[b];
    const int t0 = c * LCH_;
    const int L = seqlen[b];
    int n = L - t0;
    if (n > LCH_) n = LCH_;

    const int lane = threadIdx.x & 63, ln = lane & 15, g = lane >> 4;

    __shared__ v4f flv[4][LCH_ * 12];
    v4f* fl = flv[wid];

    s16x4 aw[3][3];
    {
        const u32x2* AF = (const u32x2*)((const char*)ws + TAF16);
        #pragma unroll
        for (int I = 0; I < 3; ++I)
            #pragma unroll
            for (int K = 0; K < 3; ++K)
                aw[I][K] = __builtin_bit_cast(s16x4, AF[(I * 3 + K) * 64 + lane]);
    }

    // stage rows t0..t0+LCH_-1 (always in-bounds), exp() applied once
    {
        constexpr int NLD = (LCH_ * 12) / 64;
        const v4f* fg = (const v4f*)(feat + ((size_t)b * SEQ + t0) * NT);
        #pragma unroll
        for (int m = 0; m < NLD; ++m) {
            v4f v = fg[m * 64 + lane];
            v4f e;
            #pragma unroll
            for (int i = 0; i < 4; ++i) e[i] = __expf(v[i]);
            fl[m * 64 + lane] = e;
        }
    }

    // init M = D_{t0} E
    s16x4 mw[3][3];
    {
        const v4f* BF = (const v4f*)((const char*)ws + TBF);
        v4f em[3];
        #pragma unroll
        for (int K = 0; K < 3; ++K) em[K] = fl[K * 4 + g];
        #pragma unroll
        for (int K = 0; K < 3; ++K)
            #pragma unroll
            for (int J = 0; J < 3; ++J) {
                v4f sc = BF[(K * 3 + J) * 64 + lane] * em[K];
                mw[K][J] = __builtin_bit_cast(s16x4,
                    (u32x2){pkbf(sc.x, sc.y), pkbf(sc.z, sc.w)});
            }
    }

    float Lc = 0.f, lg = 0.f, s = 1.f;
    const v4f kz = {0.f, 0.f, 0.f, 0.f};

    for (int t = 1; t < n; ++t) {
        v4f em[3];
        #pragma unroll
        for (int K = 0; K < 3; ++K) em[K] = fl[t * 12 + K * 4 + g];

        v4f acc[3][3];
        #pragma unroll
        for (int I = 0; I < 3; ++I)
            #pragma unroll
            for (int J = 0; J < 3; ++J)
                acc[I][J] = mfma16_z(aw[I][0], mw[0][J], kz);
        #pragma unroll
        for (int I = 0; I < 3; ++I)
            #pragma unroll
            for (int J = 0; J < 3; ++J)
                mfma16_acc(acc[I][J], aw[I][1], mw[1][J]);
        #pragma unroll
        for (int I = 0; I < 3; ++I)
            #pragma unroll
            for (int J = 0; J < 3; ++J)
                mfma16_acc(acc[I][J], aw[I][2], mw[2][J]);
        asm volatile("s_nop 7\n\ts_nop 7");
        __builtin_amdgcn_sched_barrier(0);

        const float gn = rfl(acc[0][0].x);
        Lc += lg;
        #pragma unroll
        for (int K = 0; K < 3; ++K) {
            v4f sp = em[K] * s;
            #pragma unroll
            for (int J = 0; J < 3; ++J) {
                v4f sc = acc[K][J] * sp;
                mw[K][J] = __builtin_bit_cast(s16x4,
                    (u32x2){pkbf(sc.x, sc.y), pkbf(sc.z, sc.w)});
            }
        }
        lg = __log2f(gn);
        s  = __builtin_amdgcn_rcpf(gn);
    }

    // store M^T bf16 (element M[kk][nn] -> byte 2*(nn*48+kk)) + scale
    char* wb = (char*)ws + TW + ((size_t)(b * NCH_ + c)) * 4608;
    #pragma unroll
    for (int K = 0; K < 3; ++K)
        #pragma unroll
        for (int J = 0; J < 3; ++J) {
            u32x2 w = __builtin_bit_cast(u32x2, mw[K][J]);
            *(u32*)(wb + 2 * ((J * 16 + ln) * NT + K * 16 + g * 4))     = w.x;
            *(u32*)(wb + 2 * ((J * 16 + ln) * NT + K * 16 + g * 4 + 2)) = w.y;
        }
    if (lane == 0)
        ((float*)((char*)ws + TSC))[b * NCH_ + c] = Lc;
}

// ---------------------------------------------------------------------------
// Kernel 2: per sample, u^T <- u^T * M_c for c = nb-1..0; lane j owns u[j];
// M^T row j contiguous bf16; next chunk's row double-buffered.
// ---------------------------------------------------------------------------
template<int LCH_, int NCH_>
__global__ void __launch_bounds__(64)
crf_phase2(const float* __restrict__ trans, const int* __restrict__ seqlen,
           const void* __restrict__ ws, float* __restrict__ out) {
    const int b = blockIdx.x;
    const int lane = threadIdx.x;
    const int j = (lane < NT) ? lane : (lane - 16);
    __shared__ v4f hs4[12];
    float* hs = (float*)hs4;

    const int L = seqlen[b];
    const int nb = (L + LCH_ - 1) / LCH_;
    const float* sc = (const float*)((const char*)ws + TSC) + b * NCH_;
    const char* wbase = (const char*)ws + TW + (size_t)b * NCH_ * 4608;

    float q = __expf(trans[END_TAG * NT + j]);   // u0 (exp(MIN)=0 -> col END)
    float D = 0.f;

    u32x4 buf[6];
    {
        const u32x4* wr = (const u32x4*)(wbase + (size_t)(nb - 1) * 4608 + j * 96);
        #pragma unroll
        for (int m = 0; m < 6; ++m) buf[m] = wr[m];
    }

    for (int c = nb - 1; c >= 0; --c) {
        u32x4 cur[6];
        #pragma unroll
        for (int m = 0; m < 6; ++m) cur[m] = buf[m];
        if (c > 0) {
            const u32x4* wr = (const u32x4*)(wbase + (size_t)(c - 1) * 4608 + j * 96);
            #pragma unroll
            for (int m = 0; m < 6; ++m) buf[m] = wr[m];
        }

        if (lane < NT) hs[lane] = q;
        v4f hq[12];
        #pragma unroll
        for (int k = 0; k < 12; ++k) hq[k] = hs4[k];
        const float h0 = hq[0][0];

        v2f a = {0.f, 0.f};
        #pragma unroll
        for (int m = 0; m < 6; ++m) {
            #pragma unroll
            for (int p = 0; p < 4; ++p) {
                const int i = 2 * (4 * m + p);
                u32 wv = cur[m][p];
                v2f wp;
                wp.x = bflo(wv);
                wp.y = bfhi(wv);
                v2f up = { hq[i >> 2][i & 3], hq[i >> 2][(i & 3) + 1] };
                a += wp * up;
            }
        }
        const float dot = a.x + a.y;
        q = dot * __builtin_amdgcn_rcpf(h0);
        D += __log2f(h0) + sc[c];
    }
    if (lane < NT) hs[lane] = q;
    if (lane == 0)
        out[b] = LN2f * (D + __log2f(hs[START_TAG]));
}

// ---------------------------------------------------------------------------
// Fallback: proven round-2 scalar kernel (ws too small)
// ---------------------------------------------------------------------------
__global__ void __launch_bounds__(64)
crf_scalar(const float* __restrict__ features, const float* __restrict__ transitions,
           const int* __restrict__ seq_len, float* __restrict__ out) {
    const int b = blockIdx.x;
    const int lane = threadIdx.x;
    const int j = (lane < NT) ? lane : (lane - 16);
    __shared__ v4f hs4[NT / 4];
    float* hs = (float*)hs4;

    v2f E2[NT / 2];
    {
        const v4f* trow = (const v4f*)(transitions + j * NT);
        #pragma unroll
        for (int k = 0; k < NT / 4; ++k) {
            v4f tv = trow[k];
            E2[2 * k].x = __expf(tv.x); E2[2 * k].y = __expf(tv.y);
            E2[2 * k + 1].x = __expf(tv.z); E2[2 * k + 1].y = __expf(tv.w);
        }
    }
    const float Eend = __expf(transitions[END_TAG * NT + j]);
    const int L = seq_len[b];
    const float* fbase = features + ((size_t)b * SEQ) * NT + j;

    float q = E2[START_TAG / 2].x * __expf(fbase[0]);
    float Clog2 = 0.0f;
    if (lane < NT) hs[lane] = q;

    float fb[8];
    #pragma unroll
    for (int u = 0; u < 8; ++u) {
        int tp = 1 + u;
        fb[u] = fbase[(size_t)(tp < SEQ ? tp : 0) * NT];
    }

    auto STEP = [&](float femit) {
        v4f hq[NT / 4];
        #pragma unroll
        for (int k = 0; k < NT / 4; ++k) hq[k] = hs4[k];
        float h0 = hq[0].x;
        float r = __builtin_amdgcn_rcpf(h0);
        float e = __expf(femit);
        float re = r * e;
        v2f a0 = {0.f, 0.f}, a1 = {0.f, 0.f};
        #pragma unroll
        for (int k = 0; k < NT / 4; ++k) {
            v2f lo = { hq[k].x, hq[k].y };
            v2f hi = { hq[k].z, hq[k].w };
            a0 += E2[2 * k] * lo;
            a1 += E2[2 * k + 1] * hi;
        }
        float d = (a0.x + a1.x) + (a0.y + a1.y);
        q = d * re;
        Clog2 += __log2f(h0);
        if (lane < NT) hs[lane] = q;
    };

    int t = 1;
    while (t + 8 <= L) {
        #pragma unroll
        for (int u = 0; u < 8; ++u) {
            STEP(fb[u]);
            int tp = t + u + 8;
            fb[u] = fbase[(size_t)(tp < SEQ ? tp : 0) * NT];
        }
        t += 8;
    }
    #pragma unroll
    for (int u = 0; u < 8; ++u)
        if (t + u < L) STEP(fb[u]);

    float term = (lane < NT) ? q * Eend : 0.0f;
    #pragma unroll
    for (int m = 32; m >= 1; m >>= 1) term += __shfl_xor(term, m, 64);
    if (lane == 0) out[b] = LN2f * (Clog2 + __log2f(term));
}

extern "C" void kernel_launch(void* const* d_in, const int* in_sizes, int n_in,
                              void* d_out, int out_size, void* d_ws, size_t ws_size,
                              hipStream_t stream) {
    const float* features    = (const float*)d_in[0];
    const float* transitions = (const float*)d_in[1];
    const int*   seqlen      = (const int*)d_in[2];
    float* out = (float*)d_out;

    const size_t need16 = (size_t)TW + (size_t)BATCH * 128 * 4608;  // ~151.2 MB
    const size_t need32 = (size_t)TW + (size_t)BATCH * 64 * 4608;   // ~75.7 MB
    if (ws_size >= need16) {
        crf_setup<<<1, 64, 0, stream>>>(transitions, seqlen, d_ws, 4);
        crf_phase1c<16, 128><<<8192, 256, 0, stream>>>(features, seqlen, d_ws);
        crf_phase2<16, 128><<<BATCH, 64, 0, stream>>>(transitions, seqlen, d_ws, out);
    } else if (ws_size >= need32) {
        crf_setup<<<1, 64, 0, stream>>>(transitions, seqlen, d_ws, 5);
        crf_phase1c<32, 64><<<4096, 256, 0, stream>>>(features, seqlen, d_ws);
        crf_phase2<32, 64><<<BATCH, 64, 0, stream>>>(transitions, seqlen, d_ws, out);
    } else {
        crf_scalar<<<BATCH, 64, 0, stream>>>(features, transitions, seqlen, out);
    }
}

// Round 15
// 151.740 us; speedup vs baseline: 3.3339x; 3.3339x over previous
//
#include <hip/hip_runtime.h>

#define BATCH 256
#define SEQ 2048
#define NT 48
#define START_TAG 46
#define END_TAG 47
#define LN2f  0.6931471805599453f

// ws layout
#define TAF16 0        // K16 A-frags exp(trans) bf16: [9][64] x 8B  = 4608
#define TBF   4608     // B-frag exp(trans) f32: [9][64] x 16B       = 9216
#define TCUM  13824    // prefix sums: int cum[257] (cum[0]=0)       = 1028
#define TSC   16384    // per-chunk log2 scales: [B][NCH<=128] f32   <=128KiB
#define TW    163840   // chunk matrices M^T bf16: [B][NCH][48][48]

typedef float v2f __attribute__((ext_vector_type(2)));
typedef float v4f __attribute__((ext_vector_type(4)));
typedef short s16x4 __attribute__((ext_vector_type(4)));
typedef unsigned int u32;
typedef u32 u32x2 __attribute__((ext_vector_type(2)));
typedef u32 u32x4 __attribute__((ext_vector_type(4)));

__device__ __forceinline__ u32 pkbf(float a, float b) {
    u32 r;
    asm("v_cvt_pk_bf16_f32 %0, %1, %2" : "=v"(r) : "v"(a), "v"(b));
    return r;
}
__device__ __forceinline__ float bflo(u32 w) { return __builtin_bit_cast(float, w << 16); }
__device__ __forceinline__ float bfhi(u32 w) { return __builtin_bit_cast(float, w & 0xffff0000u); }

__device__ __forceinline__ float rfl(float x) {
    return __builtin_bit_cast(float,
        __builtin_amdgcn_readfirstlane(__builtin_bit_cast(int, x)));
}

__device__ __forceinline__ v4f mfma16_z(s16x4 a, s16x4 b, v4f z) {
    v4f d;
    asm volatile("v_mfma_f32_16x16x16_bf16 %0, %2, %3, %1"
                 : "=&v"(d) : "v"(z), "v"(a), "v"(b));
    return d;
}
__device__ __forceinline__ void mfma16_acc(v4f& acc, s16x4 a, s16x4 b) {
    asm volatile("v_mfma_f32_16x16x16_bf16 %0, %1, %2, %0"
                 : "+v"(acc) : "v"(a), "v"(b));
}

// ---------------------------------------------------------------------------
// Kernel 0: exp(trans) fragments + chunk-count prefix sums (chunk = 1<<shift
// steps).  A-frag (I,K): lane holds E[I*16+(l&15)][K*16+(l>>4)*4+i], bf16.
// B-frag (K,J): lane holds E[K*16+(l>>4)*4+i][J*16+(l&15)], f32.
// ---------------------------------------------------------------------------
__global__ void __launch_bounds__(64)
crf_setup(const float* __restrict__ trans, const int* __restrict__ seqlen,
          void* ws, int shift) {
    __shared__ float el[NT * NT];
    const int lane = threadIdx.x, ln = lane & 15, g = lane >> 4;
    #pragma unroll
    for (int m = 0; m < 36; ++m) {
        int idx = lane + 64 * m;
        el[idx] = __expf(trans[idx]);
    }
    u32x2* AF = (u32x2*)((char*)ws + TAF16);
    v4f*   BF = (v4f*)((char*)ws + TBF);
    #pragma unroll
    for (int I = 0; I < 3; ++I)
        #pragma unroll
        for (int K = 0; K < 3; ++K) {
            const v4f ev = *(const v4f*)&el[(I * 16 + ln) * NT + K * 16 + g * 4];
            AF[(I * 3 + K) * 64 + lane] = (u32x2){pkbf(ev.x, ev.y), pkbf(ev.z, ev.w)};
        }
    #pragma unroll
    for (int K = 0; K < 3; ++K)
        #pragma unroll
        for (int J = 0; J < 3; ++J) {
            v4f v;
            #pragma unroll
            for (int i = 0; i < 4; ++i)
                v[i] = el[(K * 16 + g * 4 + i) * NT + J * 16 + ln];
            BF[(K * 3 + J) * 64 + lane] = v;
        }
    if (lane == 0) {
        int* cum = (int*)((char*)ws + TCUM);
        int acc = 0, mask = (1 << shift) - 1;
        for (int b = 0; b < BATCH; ++b) {
            cum[b] = acc;
            int L = seqlen[b];
            if (L < 1) L = 1;
            if (L > SEQ) L = SEQ;
            acc += (L + mask) >> shift;
        }
        cum[BATCH] = acc;
    }
}

// ---------------------------------------------------------------------------
// Kernel 1 (compacted, templated chunk size): wave widx handles the widx-th
// ACTIVE chunk (binary search over cum[]).  Per chunk: LCH_-step K16 MFMA
// chain (r13-proven): acc = E*M (27 MFMA, 3 levels x 9, asm-pinned),
// gn = raw P00, M' = acc .* (em * 1/gn_prev), Lc += log2(gn) lagged.
// Emissions pre-exp'd into wave-private LDS (LCH16: 12.3KB/WG).
// __launch_bounds__(256,4): VGPR cap 128 -> the 52-VGPR body compiles
// SPILL-FREE (r14 lesson: (256,8) = 64-VGPR cap = 1.9GB scratch traffic,
// 506us).  Residency is a HW decision upward: 52 VGPR + 12.3KB LDS admit
// up to 8 WG/CU regardless of the declared minimum.
// ---------------------------------------------------------------------------
template<int LCH_, int NCH_>
__global__ void __launch_bounds__(256, 4)
crf_phase1c(const float* __restrict__ feat, const int* __restrict__ seqlen,
            void* __restrict__ ws) {
    const int wid = threadIdx.x >> 6;
    const int widx = blockIdx.x * 4 + wid;
    const int* cum = (const int*)((const char*)ws + TCUM);
    if (widx >= cum[BATCH]) return;

    int lo = 0, hi = BATCH;          // invariant: cum[lo] <= widx < cum[hi]
    #pragma unroll
    for (int it = 0; it < 8; ++it) {
        int mid = (lo + hi) >> 1;
        if (cum[mid] <= widx) lo = mid; else hi = mid;
    }
    const int b = lo;
    const int c = widx - cum[b];
    const int t0 = c * LCH_;
    const int L = seqlen[b];
    int n = L - t0;
    if (n > LCH_) n = LCH_;

    const int lane = threadIdx.x & 63, ln = lane & 15, g = lane >> 4;

    __shared__ v4f flv[4][LCH_ * 12];
    v4f* fl = flv[wid];

    s16x4 aw[3][3];
    {
        const u32x2* AF = (const u32x2*)((const char*)ws + TAF16);
        #pragma unroll
        for (int I = 0; I < 3; ++I)
            #pragma unroll
            for (int K = 0; K < 3; ++K)
                aw[I][K] = __builtin_bit_cast(s16x4, AF[(I * 3 + K) * 64 + lane]);
    }

    // stage rows t0..t0+LCH_-1 (always in-bounds), exp() applied once
    {
        constexpr int NLD = (LCH_ * 12) / 64;
        const v4f* fg = (const v4f*)(feat + ((size_t)b * SEQ + t0) * NT);
        #pragma unroll
        for (int m = 0; m < NLD; ++m) {
            v4f v = fg[m * 64 + lane];
            v4f e;
            #pragma unroll
            for (int i = 0; i < 4; ++i) e[i] = __expf(v[i]);
            fl[m * 64 + lane] = e;
        }
    }

    // init M = D_{t0} E
    s16x4 mw[3][3];
    {
        const v4f* BF = (const v4f*)((const char*)ws + TBF);
        v4f em[3];
        #pragma unroll
        for (int K = 0; K < 3; ++K) em[K] = fl[K * 4 + g];
        #pragma unroll
        for (int K = 0; K < 3; ++K)
            #pragma unroll
            for (int J = 0; J < 3; ++J) {
                v4f sc = BF[(K * 3 + J) * 64 + lane] * em[K];
                mw[K][J] = __builtin_bit_cast(s16x4,
                    (u32x2){pkbf(sc.x, sc.y), pkbf(sc.z, sc.w)});
            }
    }

    float Lc = 0.f, lg = 0.f, s = 1.f;
    const v4f kz = {0.f, 0.f, 0.f, 0.f};

    for (int t = 1; t < n; ++t) {
        v4f em[3];
        #pragma unroll
        for (int K = 0; K < 3; ++K) em[K] = fl[t * 12 + K * 4 + g];

        v4f acc[3][3];
        #pragma unroll
        for (int I = 0; I < 3; ++I)
            #pragma unroll
            for (int J = 0; J < 3; ++J)
                acc[I][J] = mfma16_z(aw[I][0], mw[0][J], kz);
        #pragma unroll
        for (int I = 0; I < 3; ++I)
            #pragma unroll
            for (int J = 0; J < 3; ++J)
                mfma16_acc(acc[I][J], aw[I][1], mw[1][J]);
        #pragma unroll
        for (int I = 0; I < 3; ++I)
            #pragma unroll
            for (int J = 0; J < 3; ++J)
                mfma16_acc(acc[I][J], aw[I][2], mw[2][J]);
        asm volatile("s_nop 7\n\ts_nop 7");
        __builtin_amdgcn_sched_barrier(0);

        const float gn = rfl(acc[0][0].x);
        Lc += lg;
        #pragma unroll
        for (int K = 0; K < 3; ++K) {
            v4f sp = em[K] * s;
            #pragma unroll
            for (int J = 0; J < 3; ++J) {
                v4f sc = acc[K][J] * sp;
                mw[K][J] = __builtin_bit_cast(s16x4,
                    (u32x2){pkbf(sc.x, sc.y), pkbf(sc.z, sc.w)});
            }
        }
        lg = __log2f(gn);
        s  = __builtin_amdgcn_rcpf(gn);
    }

    // store M^T bf16 (element M[kk][nn] -> byte 2*(nn*48+kk)) + scale
    char* wb = (char*)ws + TW + ((size_t)(b * NCH_ + c)) * 4608;
    #pragma unroll
    for (int K = 0; K < 3; ++K)
        #pragma unroll
        for (int J = 0; J < 3; ++J) {
            u32x2 w = __builtin_bit_cast(u32x2, mw[K][J]);
            *(u32*)(wb + 2 * ((J * 16 + ln) * NT + K * 16 + g * 4))     = w.x;
            *(u32*)(wb + 2 * ((J * 16 + ln) * NT + K * 16 + g * 4 + 2)) = w.y;
        }
    if (lane == 0)
        ((float*)((char*)ws + TSC))[b * NCH_ + c] = Lc;
}

// ---------------------------------------------------------------------------
// Kernel 2: per sample, u^T <- u^T * M_c for c = nb-1..0; lane j owns u[j];
// M^T row j contiguous bf16; next chunk's row double-buffered.
// ---------------------------------------------------------------------------
template<int LCH_, int NCH_>
__global__ void __launch_bounds__(64)
crf_phase2(const float* __restrict__ trans, const int* __restrict__ seqlen,
           const void* __restrict__ ws, float* __restrict__ out) {
    const int b = blockIdx.x;
    const int lane = threadIdx.x;
    const int j = (lane < NT) ? lane : (lane - 16);
    __shared__ v4f hs4[12];
    float* hs = (float*)hs4;

    const int L = seqlen[b];
    const int nb = (L + LCH_ - 1) / LCH_;
    const float* sc = (const float*)((const char*)ws + TSC) + b * NCH_;
    const char* wbase = (const char*)ws + TW + (size_t)b * NCH_ * 4608;

    float q = __expf(trans[END_TAG * NT + j]);   // u0 (exp(MIN)=0 -> col END)
    float D = 0.f;

    u32x4 buf[6];
    {
        const u32x4* wr = (const u32x4*)(wbase + (size_t)(nb - 1) * 4608 + j * 96);
        #pragma unroll
        for (int m = 0; m < 6; ++m) buf[m] = wr[m];
    }

    for (int c = nb - 1; c >= 0; --c) {
        u32x4 cur[6];
        #pragma unroll
        for (int m = 0; m < 6; ++m) cur[m] = buf[m];
        if (c > 0) {
            const u32x4* wr = (const u32x4*)(wbase + (size_t)(c - 1) * 4608 + j * 96);
            #pragma unroll
            for (int m = 0; m < 6; ++m) buf[m] = wr[m];
        }

        if (lane < NT) hs[lane] = q;
        v4f hq[12];
        #pragma unroll
        for (int k = 0; k < 12; ++k) hq[k] = hs4[k];
        const float h0 = hq[0][0];

        v2f a = {0.f, 0.f};
        #pragma unroll
        for (int m = 0; m < 6; ++m) {
            #pragma unroll
            for (int p = 0; p < 4; ++p) {
                const int i = 2 * (4 * m + p);
                u32 wv = cur[m][p];
                v2f wp;
                wp.x = bflo(wv);
                wp.y = bfhi(wv);
                v2f up = { hq[i >> 2][i & 3], hq[i >> 2][(i & 3) + 1] };
                a += wp * up;
            }
        }
        const float dot = a.x + a.y;
        q = dot * __builtin_amdgcn_rcpf(h0);
        D += __log2f(h0) + sc[c];
    }
    if (lane < NT) hs[lane] = q;
    if (lane == 0)
        out[b] = LN2f * (D + __log2f(hs[START_TAG]));
}

// ---------------------------------------------------------------------------
// Fallback: proven round-2 scalar kernel (ws too small)
// ---------------------------------------------------------------------------
__global__ void __launch_bounds__(64)
crf_scalar(const float* __restrict__ features, const float* __restrict__ transitions,
           const int* __restrict__ seq_len, float* __restrict__ out) {
    const int b = blockIdx.x;
    const int lane = threadIdx.x;
    const int j = (lane < NT) ? lane : (lane - 16);
    __shared__ v4f hs4[NT / 4];
    float* hs = (float*)hs4;

    v2f E2[NT / 2];
    {
        const v4f* trow = (const v4f*)(transitions + j * NT);
        #pragma unroll
        for (int k = 0; k < NT / 4; ++k) {
            v4f tv = trow[k];
            E2[2 * k].x = __expf(tv.x); E2[2 * k].y = __expf(tv.y);
            E2[2 * k + 1].x = __expf(tv.z); E2[2 * k + 1].y = __expf(tv.w);
        }
    }
    const float Eend = __expf(transitions[END_TAG * NT + j]);
    const int L = seq_len[b];
    const float* fbase = features + ((size_t)b * SEQ) * NT + j;

    float q = E2[START_TAG / 2].x * __expf(fbase[0]);
    float Clog2 = 0.0f;
    if (lane < NT) hs[lane] = q;

    float fb[8];
    #pragma unroll
    for (int u = 0; u < 8; ++u) {
        int tp = 1 + u;
        fb[u] = fbase[(size_t)(tp < SEQ ? tp : 0) * NT];
    }

    auto STEP = [&](float femit) {
        v4f hq[NT / 4];
        #pragma unroll
        for (int k = 0; k < NT / 4; ++k) hq[k] = hs4[k];
        float h0 = hq[0].x;
        float r = __builtin_amdgcn_rcpf(h0);
        float e = __expf(femit);
        float re = r * e;
        v2f a0 = {0.f, 0.f}, a1 = {0.f, 0.f};
        #pragma unroll
        for (int k = 0; k < NT / 4; ++k) {
            v2f lo = { hq[k].x, hq[k].y };
            v2f hi = { hq[k].z, hq[k].w };
            a0 += E2[2 * k] * lo;
            a1 += E2[2 * k + 1] * hi;
        }
        float d = (a0.x + a1.x) + (a0.y + a1.y);
        q = d * re;
        Clog2 += __log2f(h0);
        if (lane < NT) hs[lane] = q;
    };

    int t = 1;
    while (t + 8 <= L) {
        #pragma unroll
        for (int u = 0; u < 8; ++u) {
            STEP(fb[u]);
            int tp = t + u + 8;
            fb[u] = fbase[(size_t)(tp < SEQ ? tp : 0) * NT];
        }
        t += 8;
    }
    #pragma unroll
    for (int u = 0; u < 8; ++u)
        if (t + u < L) STEP(fb[u]);

    float term = (lane < NT) ? q * Eend : 0.0f;
    #pragma unroll
    for (int m = 32; m >= 1; m >>= 1) term += __shfl_xor(term, m, 64);
    if (lane == 0) out[b] = LN2f * (Clog2 + __log2f(term));
}

extern "C" void kernel_launch(void* const* d_in, const int* in_sizes, int n_in,
                              void* d_out, int out_size, void* d_ws, size_t ws_size,
                              hipStream_t stream) {
    const float* features    = (const float*)d_in[0];
    const float* transitions = (const float*)d_in[1];
    const int*   seqlen      = (const int*)d_in[2];
    float* out = (float*)d_out;

    const size_t need16 = (size_t)TW + (size_t)BATCH * 128 * 4608;  // ~151.2 MB
    const size_t need32 = (size_t)TW + (size_t)BATCH * 64 * 4608;   // ~75.7 MB
    if (ws_size >= need16) {
        crf_setup<<<1, 64, 0, stream>>>(transitions, seqlen, d_ws, 4);
        crf_phase1c<16, 128><<<8192, 256, 0, stream>>>(features, seqlen, d_ws);
        crf_phase2<16, 128><<<BATCH, 64, 0, stream>>>(transitions, seqlen, d_ws, out);
    } else if (ws_size >= need32) {
        crf_setup<<<1, 64, 0, stream>>>(transitions, seqlen, d_ws, 5);
        crf_phase1c<32, 64><<<4096, 256, 0, stream>>>(features, seqlen, d_ws);
        crf_phase2<32, 64><<<BATCH, 64, 0, stream>>>(transitions, seqlen, d_ws, out);
    } else {
        crf_scalar<<<BATCH, 64, 0, stream>>>(features, transitions, seqlen, out);
    }
}